// Round 9
// baseline (320.023 us; speedup 1.0000x reference)
//
#include <hip/hip_runtime.h>
#include <cmath>

typedef unsigned short u16;
typedef short v8s __attribute__((ext_vector_type(8)));
typedef float v4f __attribute__((ext_vector_type(4)));
typedef unsigned short v4u __attribute__((ext_vector_type(4)));
typedef unsigned int v2u __attribute__((ext_vector_type(2)));

__device__ __forceinline__ u16 f2bf(float f) {
  unsigned u = __builtin_bit_cast(unsigned, f);
  u += 0x7fffu + ((u >> 16) & 1u);
  return (u16)(u >> 16);
}
__device__ __forceinline__ float bf2f(u16 h) {
  unsigned u = ((unsigned)h) << 16;
  return __builtin_bit_cast(float, u);
}
__device__ __forceinline__ unsigned pk2(float a, float b) {
  return (unsigned)f2bf(a) | ((unsigned)f2bf(b) << 16);
}

// ---------------- cast fp32 -> bf16 (vectorized, G13) ----------------
__global__ void k_cast_bf16(const float* __restrict__ in, u16* __restrict__ out, int n4) {
  int i = blockIdx.x * blockDim.x + threadIdx.x;
  if (i >= n4) return;
  v4f v = ((const v4f*)in)[i];
  v4u o;
  o[0] = f2bf(v[0]); o[1] = f2bf(v[1]); o[2] = f2bf(v[2]); o[3] = f2bf(v[3]);
  ((v4u*)out)[i] = o;
}

// ---------------- fused cast of the 4 weight tensors ----------------
__global__ void k_cast_w(const float* __restrict__ a, const float* __restrict__ b,
                         const float* __restrict__ c, const float* __restrict__ d,
                         u16* __restrict__ oa, u16* __restrict__ ob, u16* __restrict__ oc,
                         u16* __restrict__ od, int na4, int nb4, int nc4, int nd4) {
  int j = blockIdx.x * blockDim.x + threadIdx.x;
  const float* src;
  u16* dst;
  if (j < na4) { src = a; dst = oa; }
  else {
    j -= na4;
    if (j < nb4) { src = b; dst = ob; }
    else {
      j -= nb4;
      if (j < nc4) { src = c; dst = oc; }
      else {
        j -= nc4;
        if (j >= nd4) return;
        src = d; dst = od;
      }
    }
  }
  v4f v = ((const v4f*)src)[j];
  v4u o;
  o[0] = f2bf(v[0]); o[1] = f2bf(v[1]); o[2] = f2bf(v[2]); o[3] = f2bf(v[3]);
  ((v4u*)dst)[j] = o;
}

// ---------------- RoPE cos/sin table [S][64] f32 ----------------
__global__ void k_rope_tab(float* __restrict__ cosT, float* __restrict__ sinT, float log2_base) {
  int idx = blockIdx.x * blockDim.x + threadIdx.x;
  int t = idx >> 6, i = idx & 63;
  float inv = exp2f(-(float)i * (1.0f / 64.0f) * log2_base);
  float fr = (float)t * inv;
  cosT[idx] = cosf(fr);
  sinT[idx] = sinf(fr);
}

// ------ per-head RMSNorm + RoPE + gain + output scale (in-place, bf16) -------
__global__ void k_rmsnorm_rope(u16* __restrict__ qk, const float* __restrict__ cosT,
                               const float* __restrict__ sinT, const float* __restrict__ gain,
                               int H, int S, float oscale) {
  int row = blockIdx.x * 4 + (threadIdx.x >> 6);
  int l = threadIdx.x & 63;
  int h = row % H;
  int m = row / H;
  int s = m % S;
  u16* p = qk + (size_t)row * 128;
  float a = bf2f(p[l]), b = bf2f(p[64 + l]);
  float ss = a * a + b * b;
#pragma unroll
  for (int o = 32; o; o >>= 1) ss += __shfl_xor(ss, o, 64);
  float r = rsqrtf(ss * (1.0f / 128.0f) + 1.1920929e-7f);
  a *= r; b *= r;
  float c = cosT[s * 64 + l], sn = sinT[s * 64 + l];
  float o1 = a * c + b * sn;
  float o2 = b * c - a * sn;
  float g = oscale;
  if (gain != nullptr) g *= gain[h];
  p[l] = f2bf(o1 * g);
  p[64 + l] = f2bf(o2 * g);
}

// -------- fused QKV GEMM: [M,2048]x[3072,2048]^T -> q/k/v_t (m97 + T1) -------
__global__ __launch_bounds__(256) void k_gemm_qkv(const u16* __restrict__ A,
                                                  const u16* __restrict__ Bw,
                                                  u16* __restrict__ q_o, u16* __restrict__ k_o,
                                                  u16* __restrict__ v_o, int M, int K) {
  __shared__ u16 sA[128 * 32];
  __shared__ u16 sB[128 * 32];
  const int tid = threadIdx.x;
  const int w = tid >> 6, l = tid & 63;
  const int lr = l & 15, lh = l >> 4;
  const int wr = w >> 1, wc = w & 1;
  const int nwg = gridDim.x * gridDim.y;
  const int bid = blockIdx.y * gridDim.x + blockIdx.x;
  const int cpx = nwg >> 3;
  const int swz = (bid & 7) * cpx + (bid >> 3);
  const int row0 = (swz / gridDim.x) * 128, col0 = (swz % gridDim.x) * 128;
  v4f zz = {0.f, 0.f, 0.f, 0.f};
  v4f acc[4][4];
#pragma unroll
  for (int mi = 0; mi < 4; ++mi)
#pragma unroll
    for (int ni = 0; ni < 4; ++ni) acc[mi][ni] = zz;

  const int lrow = l >> 2;
  const int lcol = (l & 3) * 8;

  for (int k0 = 0; k0 < K; k0 += 32) {
#pragma unroll
    for (int i = 0; i < 2; ++i) {
      int c = i * 4 + w;
      const u16* srcA = A + (size_t)(row0 + c * 16 + lrow) * K + (k0 + lcol);
      const u16* srcB = Bw + (size_t)(col0 + c * 16 + lrow) * K + (k0 + lcol);
      __builtin_amdgcn_global_load_lds((const __attribute__((address_space(1))) void*)srcA,
                                       (__attribute__((address_space(3))) void*)(sA + c * 512),
                                       16, 0, 0);
      __builtin_amdgcn_global_load_lds((const __attribute__((address_space(1))) void*)srcB,
                                       (__attribute__((address_space(3))) void*)(sB + c * 512),
                                       16, 0, 0);
    }
    __syncthreads();
    v8s af[4], bfr[4];
#pragma unroll
    for (int mi = 0; mi < 4; ++mi)
      af[mi] = *(const v8s*)(sA + (wr * 64 + mi * 16 + lr) * 32 + lh * 8);
#pragma unroll
    for (int ni = 0; ni < 4; ++ni)
      bfr[ni] = *(const v8s*)(sB + (wc * 64 + ni * 16 + lr) * 32 + lh * 8);
#pragma unroll
    for (int mi = 0; mi < 4; ++mi)
#pragma unroll
      for (int ni = 0; ni < 4; ++ni)
        acc[mi][ni] = __builtin_amdgcn_mfma_f32_16x16x32_bf16(af[mi], bfr[ni], acc[mi][ni], 0, 0, 0);
    __syncthreads();
  }
  u16* outp;
  int ldo = 0, cb;
  bool tr = false;
  if (col0 < 2048) { outp = q_o; ldo = 2048; cb = col0; }
  else if (col0 < 2560) { outp = k_o; ldo = 512; cb = col0 - 2048; }
  else { outp = v_o; tr = true; cb = col0 - 2560; }
#pragma unroll
  for (int mi = 0; mi < 4; ++mi) {
#pragma unroll
    for (int ni = 0; ni < 4; ++ni) {
      int row = row0 + wr * 64 + mi * 16 + lh * 4;
      int col = cb + wc * 64 + ni * 16 + lr;
#pragma unroll
      for (int r = 0; r < 4; ++r) {
        u16 bv = f2bf(acc[mi][ni][r]);
        if (tr) outp[(size_t)col * M + row + r] = bv;
        else    outp[(size_t)(row + r) * ldo + col] = bv;
      }
    }
  }
}

// ---------------- out-proj GEMM: C[M,N] = A[M,K] * Bw[N,K]^T (m97 + T1) ------
__global__ __launch_bounds__(256) void k_gemm_bt(const u16* __restrict__ A,
                                                 const u16* __restrict__ Bw,
                                                 float* __restrict__ C, int M, int N, int K) {
  __shared__ u16 sA[128 * 32];
  __shared__ u16 sB[128 * 32];
  const int tid = threadIdx.x;
  const int w = tid >> 6, l = tid & 63;
  const int lr = l & 15, lh = l >> 4;
  const int wr = w >> 1, wc = w & 1;
  const int nwg = gridDim.x * gridDim.y;
  const int bid = blockIdx.y * gridDim.x + blockIdx.x;
  const int cpx = nwg >> 3;
  const int swz = (bid & 7) * cpx + (bid >> 3);
  const int row0 = (swz / gridDim.x) * 128, col0 = (swz % gridDim.x) * 128;
  v4f zz = {0.f, 0.f, 0.f, 0.f};
  v4f acc[4][4];
#pragma unroll
  for (int mi = 0; mi < 4; ++mi)
#pragma unroll
    for (int ni = 0; ni < 4; ++ni) acc[mi][ni] = zz;

  const int lrow = l >> 2;
  const int lcol = (l & 3) * 8;

  for (int k0 = 0; k0 < K; k0 += 32) {
#pragma unroll
    for (int i = 0; i < 2; ++i) {
      int c = i * 4 + w;
      const u16* srcA = A + (size_t)(row0 + c * 16 + lrow) * K + (k0 + lcol);
      const u16* srcB = Bw + (size_t)(col0 + c * 16 + lrow) * K + (k0 + lcol);
      __builtin_amdgcn_global_load_lds((const __attribute__((address_space(1))) void*)srcA,
                                       (__attribute__((address_space(3))) void*)(sA + c * 512),
                                       16, 0, 0);
      __builtin_amdgcn_global_load_lds((const __attribute__((address_space(1))) void*)srcB,
                                       (__attribute__((address_space(3))) void*)(sB + c * 512),
                                       16, 0, 0);
    }
    __syncthreads();
    v8s af[4], bfr[4];
#pragma unroll
    for (int mi = 0; mi < 4; ++mi)
      af[mi] = *(const v8s*)(sA + (wr * 64 + mi * 16 + lr) * 32 + lh * 8);
#pragma unroll
    for (int ni = 0; ni < 4; ++ni)
      bfr[ni] = *(const v8s*)(sB + (wc * 64 + ni * 16 + lr) * 32 + lh * 8);
#pragma unroll
    for (int mi = 0; mi < 4; ++mi)
#pragma unroll
      for (int ni = 0; ni < 4; ++ni)
        acc[mi][ni] = __builtin_amdgcn_mfma_f32_16x16x32_bf16(af[mi], bfr[ni], acc[mi][ni], 0, 0, 0);
    __syncthreads();
  }
#pragma unroll
  for (int mi = 0; mi < 4; ++mi) {
#pragma unroll
    for (int ni = 0; ni < 4; ++ni) {
      int row = row0 + wr * 64 + mi * 16 + lh * 4;
      int col = col0 + wc * 64 + ni * 16 + lr;
#pragma unroll
      for (int r = 0; r < 4; ++r) C[(size_t)(row + r) * N + col] = acc[mi][ni][r];
    }
  }
}

// ------------- causal GQA flash attention v9: 128-row tiles, 2 subs/wave -----
// Wave owns 32 q-rows as two 16-row subtiles sharing kf ds_reads and V frags
// (V bytes, K reads, K staging per row all halved vs 64-row blocks).
// grid (B*H, 16): slot<8 = head of qtile j=8+slot, kv[0,17) (17u, partial 0).
// slot>=8 (s2): tail of j=8+s2, kv[17,2j+2) (2j-15 u, partial 1), then full
// short j'=7-s2 (16-2s2 u, final). All slots = exactly 17 units; 512 blocks
// = 2/CU all co-resident (reg cap is 2 waves/SIMD incl. hidden AGPRs).
__global__ __launch_bounds__(256) void k_flash_attn(
    const u16* __restrict__ Q, const u16* __restrict__ Kb, const u16* __restrict__ Vt,
    u16* __restrict__ O, u16* __restrict__ o_part, float* __restrict__ m_part,
    float* __restrict__ l_part, int S, int H, int KH, int Mtot) {
  const int bh = blockIdx.x;
  const int slot = blockIdx.y;
  const int h = bh % H, b = bh / H;
  const int kvh = h / (H / KH);
  const int w = threadIdx.x >> 6, l = threadIdx.x & 63;
  const int lr = l & 15, lh = l >> 4;

  __shared__ alignas(16) char sK[2][16384];               // 64 kv x 256B, swizzled
  __shared__ alignas(16) unsigned P_lds[4][2][16 * 32];   // per-wave per-sub packed P
  const int xr = (lr & 7) << 2;

  v4f zz = {0.f, 0.f, 0.f, 0.f};
  const int strideK = KH * 128;
  const int strideKB = strideK * 2;
  const char* KheadB = (const char*)Kb + 2 * ((size_t)b * S * strideK + (size_t)kvh * 128);
  const u16* Vbase = Vt + (size_t)(kvh * 128) * Mtot + (size_t)b * S;

  const int nseg = (slot < 8) ? 1 : 2;
  for (int seg = 0; seg < nseg; ++seg) {
    int j, t0, t1, pidx;
    bool fin;
    if (slot < 8) {
      j = 8 + slot; t0 = 0; t1 = 17; fin = false; pidx = 0;
    } else {
      const int s2 = slot - 8;
      if (seg == 0) { j = 8 + s2; t0 = 17; t1 = 18 + 2 * s2; fin = false; pidx = 1; }
      else          { j = 7 - s2; t0 = 0;  t1 = 16 - 2 * s2; fin = true;  pidx = 0; }
    }
    const int q0 = j * 128;

    v8s qf[2][4];
#pragma unroll
    for (int s = 0; s < 2; ++s) {
      const u16* qp =
          Q + (size_t)(b * S + q0 + w * 32 + s * 16 + lr) * (size_t)(H * 128) + h * 128 + lh * 8;
#pragma unroll
      for (int c = 0; c < 4; ++c) qf[s][c] = *(const v8s*)(qp + c * 32);
    }

    v4f o_acc[2][8];
    float m_run[2], l_run[2];
#pragma unroll
    for (int s = 0; s < 2; ++s) {
      m_run[s] = -1e30f; l_run[s] = 0.f;
#pragma unroll
      for (int df = 0; df < 8; ++df) o_acc[s][df] = zz;
    }

    // prologue: stage tile t0 into buf 0 (16 chunks, 4 per wave)
    {
      const char* Kt = KheadB + (size_t)(t0 * 64) * strideKB;
#pragma unroll
      for (int jj2 = 0; jj2 < 4; ++jj2) {
        int jj = w * 4 + jj2;
        int ci = jj * 64 + l;
        int r = ci >> 4;
        int bc = (ci & 15) << 4;
        const char* src = Kt + (size_t)r * strideKB + (bc ^ ((r & 15) << 4));
        __builtin_amdgcn_global_load_lds((const __attribute__((address_space(1))) void*)src,
                                         (__attribute__((address_space(3))) void*)(sK[0] + jj * 1024),
                                         16, 0, 0);
      }
    }
    __syncthreads();

    int buf = 0;
    for (int t = t0; t < t1; ++t) {
      const int kv0 = t * 64;
      const bool maskTile = (kv0 + 63 > q0);  // block-uniform gate; per-lane mask inside
      const char* sKb = sK[buf];

      // ---- QK^T both subs, ONE kf read each (swapped: C rows = kv, cols = q) ----
      v4f sv[2][4];
      __builtin_amdgcn_s_setprio(1);
#pragma unroll
      for (int nf = 0; nf < 4; ++nf) {
        v4f a0 = zz, a1 = zz;
        const int r = nf * 16 + lr;
#pragma unroll
        for (int c = 0; c < 4; ++c) {
          v8s kf = *(const v8s*)(sKb + r * 256 + ((lh * 16 + c * 64) ^ (lr << 4)));
          a0 = __builtin_amdgcn_mfma_f32_16x16x32_bf16(kf, qf[0][c], a0, 0, 0, 0);
          a1 = __builtin_amdgcn_mfma_f32_16x16x32_bf16(kf, qf[1][c], a1, 0, 0, 0);
        }
        sv[0][nf] = a0;
        sv[1][nf] = a1;
      }
      __builtin_amdgcn_s_setprio(0);

      // ---- V chunk A (d 0..63) prefetch: shared by both subs ----
      v8s vf[4][2];
#pragma unroll
      for (int df = 0; df < 4; ++df) {
        const u16* vp = Vbase + (size_t)(df * 16 + lr) * Mtot + kv0 + lh * 8;
#pragma unroll
        for (int c2 = 0; c2 < 2; ++c2) vf[df][c2] = *(const v8s*)(vp + c2 * 32);
      }

      // ---- stage next K tile ----
      if (t + 1 < t1) {
        const char* Kt = KheadB + (size_t)(kv0 + 64) * strideKB;
        char* dst = (char*)sK[buf ^ 1];
#pragma unroll
        for (int jj2 = 0; jj2 < 4; ++jj2) {
          int jj = w * 4 + jj2;
          int ci = jj * 64 + l;
          int r = ci >> 4;
          int bc = (ci & 15) << 4;
          const char* src = Kt + (size_t)r * strideKB + (bc ^ ((r & 15) << 4));
          __builtin_amdgcn_global_load_lds((const __attribute__((address_space(1))) void*)src,
                                           (__attribute__((address_space(3))) void*)(dst + jj * 1024),
                                           16, 0, 0);
        }
      }

      // ---- softmax per sub (in-lane, defer-max) + pack P to per-sub LDS ----
#pragma unroll
      for (int s = 0; s < 2; ++s) {
        const int qi = q0 + w * 32 + s * 16 + lr;
        if (maskTile) {
#pragma unroll
          for (int nf = 0; nf < 4; ++nf)
#pragma unroll
            for (int r = 0; r < 4; ++r)
              if (kv0 + nf * 16 + lh * 4 + r > qi) sv[s][nf][r] = -1e30f;
        }
        float pmax = -1e30f;
#pragma unroll
        for (int nf = 0; nf < 4; ++nf)
#pragma unroll
          for (int r = 0; r < 4; ++r) pmax = fmaxf(pmax, sv[s][nf][r]);
        pmax = fmaxf(pmax, __shfl_xor(pmax, 16, 64));
        pmax = fmaxf(pmax, __shfl_xor(pmax, 32, 64));
        if (!__all(pmax - m_run[s] <= 8.0f)) {  // T13 defer-max
          float mnew = fmaxf(m_run[s], pmax);
          float corr = exp2f(m_run[s] - mnew);
          l_run[s] *= corr;
          m_run[s] = mnew;
          float corrq[4];
#pragma unroll
          for (int r = 0; r < 4; ++r) corrq[r] = __shfl(corr, lh * 4 + r, 16);
#pragma unroll
          for (int df = 0; df < 8; ++df)
#pragma unroll
            for (int r = 0; r < 4; ++r) o_acc[s][df][r] *= corrq[r];
        }
        float rsum = 0.f;
#pragma unroll
        for (int nf = 0; nf < 4; ++nf)
#pragma unroll
          for (int r = 0; r < 4; ++r) {
            float pv = exp2f(sv[s][nf][r] - m_run[s]);
            sv[s][nf][r] = pv;
            rsum += pv;
          }
        rsum += __shfl_xor(rsum, 16, 64);
        rsum += __shfl_xor(rsum, 32, 64);
        l_run[s] += rsum;

        unsigned* prow = P_lds[w][s] + lr * 32;
#pragma unroll
        for (int nf = 0; nf < 4; ++nf) {
          v2u pw;
          pw[0] = pk2(sv[s][nf][0], sv[s][nf][1]);
          pw[1] = pk2(sv[s][nf][2], sv[s][nf][3]);
          *(v2u*)(prow + ((nf * 8 + lh * 2) ^ xr)) = pw;
        }
      }
      asm volatile("s_waitcnt lgkmcnt(0)" ::: "memory");
      __builtin_amdgcn_sched_barrier(0);  // rule 18
      v8s ap[2][2];
#pragma unroll
      for (int s = 0; s < 2; ++s) {
        unsigned* prow = P_lds[w][s] + lr * 32;
#pragma unroll
        for (int c2 = 0; c2 < 2; ++c2)
          ap[s][c2] = *(const v8s*)(prow + ((c2 * 16 + lh * 4) ^ xr));
      }

      // ---- PV chunk A (d 0..63), both subs share vf ----
      __builtin_amdgcn_s_setprio(1);
#pragma unroll
      for (int df = 0; df < 4; ++df)
#pragma unroll
        for (int c2 = 0; c2 < 2; ++c2) {
          o_acc[0][df] =
              __builtin_amdgcn_mfma_f32_16x16x32_bf16(ap[0][c2], vf[df][c2], o_acc[0][df], 0, 0, 0);
          o_acc[1][df] =
              __builtin_amdgcn_mfma_f32_16x16x32_bf16(ap[1][c2], vf[df][c2], o_acc[1][df], 0, 0, 0);
        }
      __builtin_amdgcn_s_setprio(0);
      __builtin_amdgcn_sched_barrier(0);  // keep chunk-B loads below chunk-A MFMAs

      // ---- V chunk B (d 64..127) reload into same regs, PV both subs ----
#pragma unroll
      for (int df = 0; df < 4; ++df) {
        const u16* vp = Vbase + (size_t)((df + 4) * 16 + lr) * Mtot + kv0 + lh * 8;
#pragma unroll
        for (int c2 = 0; c2 < 2; ++c2) vf[df][c2] = *(const v8s*)(vp + c2 * 32);
      }
      __builtin_amdgcn_s_setprio(1);
#pragma unroll
      for (int df = 0; df < 4; ++df)
#pragma unroll
        for (int c2 = 0; c2 < 2; ++c2) {
          o_acc[0][df + 4] = __builtin_amdgcn_mfma_f32_16x16x32_bf16(ap[0][c2], vf[df][c2],
                                                                    o_acc[0][df + 4], 0, 0, 0);
          o_acc[1][df + 4] = __builtin_amdgcn_mfma_f32_16x16x32_bf16(ap[1][c2], vf[df][c2],
                                                                    o_acc[1][df + 4], 0, 0, 0);
        }
      __builtin_amdgcn_s_setprio(0);

      __syncthreads();
      buf ^= 1;
    }

    if (fin) {
#pragma unroll
      for (int s = 0; s < 2; ++s) {
        float rl = 1.0f / l_run[s];
        float invq[4];
#pragma unroll
        for (int r = 0; r < 4; ++r) invq[r] = __shfl(rl, lh * 4 + r, 16);
        u16* op = O + (size_t)(b * S + q0 + w * 32 + s * 16 + lh * 4) * (size_t)(H * 128) + h * 128;
#pragma unroll
        for (int r = 0; r < 4; ++r)
#pragma unroll
          for (int df = 0; df < 8; ++df)
            op[(size_t)r * (H * 128) + df * 16 + lr] = f2bf(o_acc[s][df][r] * invq[r]);
      }
    } else {
      const size_t idx = ((size_t)(pidx * 32 + bh)) * 8 + (j - 8);
#pragma unroll
      for (int s = 0; s < 2; ++s) {
        u16* op = o_part + idx * 16384 + (size_t)(w * 32 + s * 16 + lh * 4) * 128;
#pragma unroll
        for (int r = 0; r < 4; ++r)
#pragma unroll
          for (int df = 0; df < 8; ++df)
            op[(size_t)r * 128 + df * 16 + lr] = f2bf(o_acc[s][df][r]);
        if (lh == 0) {
          size_t mi = idx * 128 + (w * 32 + s * 16 + lr);
          m_part[mi] = m_run[s];
          l_part[mi] = l_run[s];
        }
      }
    }
  }
}

// ---------------- merge head+tail partials of each long q-tile (128 rows) ----
__global__ __launch_bounds__(256) void k_merge(const u16* __restrict__ o_part,
                                               const float* __restrict__ m_part,
                                               const float* __restrict__ l_part,
                                               u16* __restrict__ ao, int S, int H) {
  const int bh = blockIdx.x;   // 32
  const int j2 = blockIdx.y;   // 8
  const int h = bh % H, b = bh / H;
  const int q0 = (8 + j2) * 128;
  const int tid = threadIdx.x;
  const size_t i0 = (size_t)bh * 8 + j2;
  const size_t i1 = (size_t)(32 + bh) * 8 + j2;
#pragma unroll
  for (int i = 0; i < 8; ++i) {
    int c = i * 256 + tid;  // 0..2047 (128 rows x 16 vec8)
    int row = c >> 4, c8 = c & 15;
    float m0 = m_part[i0 * 128 + row], m1 = m_part[i1 * 128 + row];
    float l0 = l_part[i0 * 128 + row], l1 = l_part[i1 * 128 + row];
    float m = fmaxf(m0, m1);
    float a0 = exp2f(m0 - m), a1 = exp2f(m1 - m);
    float inv = 1.0f / (l0 * a0 + l1 * a1);
    a0 *= inv; a1 *= inv;
    v8s x0 = *(const v8s*)(o_part + i0 * 16384 + row * 128 + c8 * 8);
    v8s x1 = *(const v8s*)(o_part + i1 * 16384 + row * 128 + c8 * 8);
    v8s res;
#pragma unroll
    for (int e = 0; e < 8; ++e)
      res[e] = (short)f2bf(bf2f((u16)x0[e]) * a0 + bf2f((u16)x1[e]) * a1);
    *(v8s*)(ao + (size_t)(b * S + q0 + row) * (size_t)(H * 128) + h * 128 + c8 * 8) = res;
  }
}

extern "C" void kernel_launch(void* const* d_in, const int* in_sizes, int n_in, void* d_out,
                              int out_size, void* d_ws, size_t ws_size, hipStream_t stream) {
  const float* x = (const float*)d_in[0];
  const float* Wq = (const float*)d_in[1];
  const float* Wk = (const float*)d_in[2];
  const float* Wv = (const float*)d_in[3];
  const float* Wp = (const float*)d_in[4];
  const float* gain = (const float*)d_in[5];
  float* out = (float*)d_out;

  const int B = 2, S = 2048, D = 2048, H = 16, KH = 4;
  const int M = B * S;
  const int KVD = KH * 128;
  const int NQKV = D + 2 * KVD;  // 3072

  char* w = (char*)d_ws;
  u16* x_bf = (u16*)w;   w += (size_t)M * D * 2;
  u16* wqkv = (u16*)w;   w += (size_t)NQKV * D * 2;
  u16* wp_bf = (u16*)w;  w += (size_t)D * D * 2;
  u16* q_bf = (u16*)w;   w += (size_t)M * D * 2;
  u16* k_bf = (u16*)w;   w += (size_t)M * KVD * 2;
  u16* v_t = (u16*)w;    w += (size_t)M * KVD * 2;
  u16* ao_bf = (u16*)w;  w += (size_t)M * D * 2;
  float* cosT = (float*)w; w += (size_t)S * 64 * 4;
  float* sinT = (float*)w; w += (size_t)S * 64 * 4;
  if ((size_t)(w - (char*)d_ws) > ws_size) return;
  // attention partials alias regions dead after the QKV GEMM:
  u16* o_part = x_bf;                  // 2*32*8*16384 u16 = 16.78 MB (== x_bf size)
  float* m_part = (float*)wqkv;        // 2*32*8*128 f32 = 256 KB
  float* l_part = m_part + 2 * 32 * 8 * 128;

  k_cast_bf16<<<(M * D / 4 + 255) / 256, 256, 0, stream>>>(x, x_bf, M * D / 4);
  {
    int na4 = D * D / 4, nb4 = KVD * D / 4, nc4 = KVD * D / 4, nd4 = D * D / 4;
    int tot = na4 + nb4 + nc4 + nd4;
    k_cast_w<<<(tot + 255) / 256, 256, 0, stream>>>(
        Wq, Wk, Wv, Wp, wqkv, wqkv + (size_t)D * D, wqkv + (size_t)(D + KVD) * D, wp_bf,
        na4, nb4, nc4, nd4);
  }

  double scale = (double)S / 1024.0;
  double base = (S > 1024) ? 10000.0 * pow(scale, 128.0 / 126.0) : 10000.0;
  float l2b = (float)(log(base) / log(2.0));
  k_rope_tab<<<S * 64 / 256, 256, 0, stream>>>(cosT, sinT, l2b);

  dim3 blk(256);
  dim3 gqkv(NQKV / 128, M / 128);  // 24 x 32 = 768 blocks
  k_gemm_qkv<<<gqkv, blk, 0, stream>>>(x_bf, wqkv, q_bf, k_bf, v_t, M, D);

  float qscale = 1.4426950408889634f / sqrtf(128.0f);
  k_rmsnorm_rope<<<(M * H) / 4, 256, 0, stream>>>(q_bf, cosT, sinT, gain, H, S, qscale);
  k_rmsnorm_rope<<<(M * KH) / 4, 256, 0, stream>>>(k_bf, cosT, sinT, nullptr, KH, S, 1.0f);

  dim3 ga(B * H, 16);  // 512 blocks, exactly 17 tile-units each, 2/CU co-resident
  k_flash_attn<<<ga, blk, 0, stream>>>(q_bf, k_bf, v_t, ao_bf, o_part, m_part, l_part,
                                       S, H, KH, M);
  dim3 gm(B * H, 8);
  k_merge<<<gm, blk, 0, stream>>>(o_part, m_part, l_part, ao_bf, S, H);

  dim3 gp(D / 128, M / 128);
  k_gemm_bt<<<gp, blk, 0, stream>>>(ao_bf, wp_bf, out, M, D, D);
}

// Round 10
// 248.483 us; speedup vs baseline: 1.2879x; 1.2879x over previous
//
#include <hip/hip_runtime.h>
#include <cmath>

typedef unsigned short u16;
typedef short v8s __attribute__((ext_vector_type(8)));
typedef float v4f __attribute__((ext_vector_type(4)));
typedef unsigned short v4u __attribute__((ext_vector_type(4)));
typedef unsigned int v2u __attribute__((ext_vector_type(2)));

__device__ __forceinline__ u16 f2bf(float f) {
  unsigned u = __builtin_bit_cast(unsigned, f);
  u += 0x7fffu + ((u >> 16) & 1u);
  return (u16)(u >> 16);
}
__device__ __forceinline__ float bf2f(u16 h) {
  unsigned u = ((unsigned)h) << 16;
  return __builtin_bit_cast(float, u);
}
__device__ __forceinline__ unsigned pk2(float a, float b) {
  return (unsigned)f2bf(a) | ((unsigned)f2bf(b) << 16);
}

// ---------------- cast fp32 -> bf16 (vectorized, G13) ----------------
__global__ void k_cast_bf16(const float* __restrict__ in, u16* __restrict__ out, int n4) {
  int i = blockIdx.x * blockDim.x + threadIdx.x;
  if (i >= n4) return;
  v4f v = ((const v4f*)in)[i];
  v4u o;
  o[0] = f2bf(v[0]); o[1] = f2bf(v[1]); o[2] = f2bf(v[2]); o[3] = f2bf(v[3]);
  ((v4u*)out)[i] = o;
}

// ---------------- fused cast of the 4 weight tensors ----------------
__global__ void k_cast_w(const float* __restrict__ a, const float* __restrict__ b,
                         const float* __restrict__ c, const float* __restrict__ d,
                         u16* __restrict__ oa, u16* __restrict__ ob, u16* __restrict__ oc,
                         u16* __restrict__ od, int na4, int nb4, int nc4, int nd4) {
  int j = blockIdx.x * blockDim.x + threadIdx.x;
  const float* src;
  u16* dst;
  if (j < na4) { src = a; dst = oa; }
  else {
    j -= na4;
    if (j < nb4) { src = b; dst = ob; }
    else {
      j -= nb4;
      if (j < nc4) { src = c; dst = oc; }
      else {
        j -= nc4;
        if (j >= nd4) return;
        src = d; dst = od;
      }
    }
  }
  v4f v = ((const v4f*)src)[j];
  v4u o;
  o[0] = f2bf(v[0]); o[1] = f2bf(v[1]); o[2] = f2bf(v[2]); o[3] = f2bf(v[3]);
  ((v4u*)dst)[j] = o;
}

// ---------------- RoPE cos/sin table [S][64] f32 ----------------
__global__ void k_rope_tab(float* __restrict__ cosT, float* __restrict__ sinT, float log2_base) {
  int idx = blockIdx.x * blockDim.x + threadIdx.x;
  int t = idx >> 6, i = idx & 63;
  float inv = exp2f(-(float)i * (1.0f / 64.0f) * log2_base);
  float fr = (float)t * inv;
  cosT[idx] = cosf(fr);
  sinT[idx] = sinf(fr);
}

// ------ per-head RMSNorm + RoPE + gain + output scale (in-place, bf16) -------
__global__ void k_rmsnorm_rope(u16* __restrict__ qk, const float* __restrict__ cosT,
                               const float* __restrict__ sinT, const float* __restrict__ gain,
                               int H, int S, float oscale) {
  int row = blockIdx.x * 4 + (threadIdx.x >> 6);
  int l = threadIdx.x & 63;
  int h = row % H;
  int m = row / H;
  int s = m % S;
  u16* p = qk + (size_t)row * 128;
  float a = bf2f(p[l]), b = bf2f(p[64 + l]);
  float ss = a * a + b * b;
#pragma unroll
  for (int o = 32; o; o >>= 1) ss += __shfl_xor(ss, o, 64);
  float r = rsqrtf(ss * (1.0f / 128.0f) + 1.1920929e-7f);
  a *= r; b *= r;
  float c = cosT[s * 64 + l], sn = sinT[s * 64 + l];
  float o1 = a * c + b * sn;
  float o2 = b * c - a * sn;
  float g = oscale;
  if (gain != nullptr) g *= gain[h];
  p[l] = f2bf(o1 * g);
  p[64 + l] = f2bf(o2 * g);
}

// -------- fused QKV GEMM: [M,2048]x[3072,2048]^T -> q/k/v_t (m97 + T1) -------
__global__ __launch_bounds__(256) void k_gemm_qkv(const u16* __restrict__ A,
                                                  const u16* __restrict__ Bw,
                                                  u16* __restrict__ q_o, u16* __restrict__ k_o,
                                                  u16* __restrict__ v_o, int M, int K) {
  __shared__ u16 sA[128 * 32];
  __shared__ u16 sB[128 * 32];
  const int tid = threadIdx.x;
  const int w = tid >> 6, l = tid & 63;
  const int lr = l & 15, lh = l >> 4;
  const int wr = w >> 1, wc = w & 1;
  const int nwg = gridDim.x * gridDim.y;
  const int bid = blockIdx.y * gridDim.x + blockIdx.x;
  const int cpx = nwg >> 3;
  const int swz = (bid & 7) * cpx + (bid >> 3);
  const int row0 = (swz / gridDim.x) * 128, col0 = (swz % gridDim.x) * 128;
  v4f zz = {0.f, 0.f, 0.f, 0.f};
  v4f acc[4][4];
#pragma unroll
  for (int mi = 0; mi < 4; ++mi)
#pragma unroll
    for (int ni = 0; ni < 4; ++ni) acc[mi][ni] = zz;

  const int lrow = l >> 2;
  const int lcol = (l & 3) * 8;

  for (int k0 = 0; k0 < K; k0 += 32) {
#pragma unroll
    for (int i = 0; i < 2; ++i) {
      int c = i * 4 + w;
      const u16* srcA = A + (size_t)(row0 + c * 16 + lrow) * K + (k0 + lcol);
      const u16* srcB = Bw + (size_t)(col0 + c * 16 + lrow) * K + (k0 + lcol);
      __builtin_amdgcn_global_load_lds((const __attribute__((address_space(1))) void*)srcA,
                                       (__attribute__((address_space(3))) void*)(sA + c * 512),
                                       16, 0, 0);
      __builtin_amdgcn_global_load_lds((const __attribute__((address_space(1))) void*)srcB,
                                       (__attribute__((address_space(3))) void*)(sB + c * 512),
                                       16, 0, 0);
    }
    __syncthreads();
    v8s af[4], bfr[4];
#pragma unroll
    for (int mi = 0; mi < 4; ++mi)
      af[mi] = *(const v8s*)(sA + (wr * 64 + mi * 16 + lr) * 32 + lh * 8);
#pragma unroll
    for (int ni = 0; ni < 4; ++ni)
      bfr[ni] = *(const v8s*)(sB + (wc * 64 + ni * 16 + lr) * 32 + lh * 8);
#pragma unroll
    for (int mi = 0; mi < 4; ++mi)
#pragma unroll
      for (int ni = 0; ni < 4; ++ni)
        acc[mi][ni] = __builtin_amdgcn_mfma_f32_16x16x32_bf16(af[mi], bfr[ni], acc[mi][ni], 0, 0, 0);
    __syncthreads();
  }
  u16* outp;
  int ldo = 0, cb;
  bool tr = false;
  if (col0 < 2048) { outp = q_o; ldo = 2048; cb = col0; }
  else if (col0 < 2560) { outp = k_o; ldo = 512; cb = col0 - 2048; }
  else { outp = v_o; tr = true; cb = col0 - 2560; }
#pragma unroll
  for (int mi = 0; mi < 4; ++mi) {
#pragma unroll
    for (int ni = 0; ni < 4; ++ni) {
      int row = row0 + wr * 64 + mi * 16 + lh * 4;
      int col = cb + wc * 64 + ni * 16 + lr;
#pragma unroll
      for (int r = 0; r < 4; ++r) {
        u16 bv = f2bf(acc[mi][ni][r]);
        if (tr) outp[(size_t)col * M + row + r] = bv;
        else    outp[(size_t)(row + r) * ldo + col] = bv;
      }
    }
  }
}

// ---------------- out-proj GEMM: C[M,N] = A[M,K] * Bw[N,K]^T (m97 + T1) ------
__global__ __launch_bounds__(256) void k_gemm_bt(const u16* __restrict__ A,
                                                 const u16* __restrict__ Bw,
                                                 float* __restrict__ C, int M, int N, int K) {
  __shared__ u16 sA[128 * 32];
  __shared__ u16 sB[128 * 32];
  const int tid = threadIdx.x;
  const int w = tid >> 6, l = tid & 63;
  const int lr = l & 15, lh = l >> 4;
  const int wr = w >> 1, wc = w & 1;
  const int nwg = gridDim.x * gridDim.y;
  const int bid = blockIdx.y * gridDim.x + blockIdx.x;
  const int cpx = nwg >> 3;
  const int swz = (bid & 7) * cpx + (bid >> 3);
  const int row0 = (swz / gridDim.x) * 128, col0 = (swz % gridDim.x) * 128;
  v4f zz = {0.f, 0.f, 0.f, 0.f};
  v4f acc[4][4];
#pragma unroll
  for (int mi = 0; mi < 4; ++mi)
#pragma unroll
    for (int ni = 0; ni < 4; ++ni) acc[mi][ni] = zz;

  const int lrow = l >> 2;
  const int lcol = (l & 3) * 8;

  for (int k0 = 0; k0 < K; k0 += 32) {
#pragma unroll
    for (int i = 0; i < 2; ++i) {
      int c = i * 4 + w;
      const u16* srcA = A + (size_t)(row0 + c * 16 + lrow) * K + (k0 + lcol);
      const u16* srcB = Bw + (size_t)(col0 + c * 16 + lrow) * K + (k0 + lcol);
      __builtin_amdgcn_global_load_lds((const __attribute__((address_space(1))) void*)srcA,
                                       (__attribute__((address_space(3))) void*)(sA + c * 512),
                                       16, 0, 0);
      __builtin_amdgcn_global_load_lds((const __attribute__((address_space(1))) void*)srcB,
                                       (__attribute__((address_space(3))) void*)(sB + c * 512),
                                       16, 0, 0);
    }
    __syncthreads();
    v8s af[4], bfr[4];
#pragma unroll
    for (int mi = 0; mi < 4; ++mi)
      af[mi] = *(const v8s*)(sA + (wr * 64 + mi * 16 + lr) * 32 + lh * 8);
#pragma unroll
    for (int ni = 0; ni < 4; ++ni)
      bfr[ni] = *(const v8s*)(sB + (wc * 64 + ni * 16 + lr) * 32 + lh * 8);
#pragma unroll
    for (int mi = 0; mi < 4; ++mi)
#pragma unroll
      for (int ni = 0; ni < 4; ++ni)
        acc[mi][ni] = __builtin_amdgcn_mfma_f32_16x16x32_bf16(af[mi], bfr[ni], acc[mi][ni], 0, 0, 0);
    __syncthreads();
  }
#pragma unroll
  for (int mi = 0; mi < 4; ++mi) {
#pragma unroll
    for (int ni = 0; ni < 4; ++ni) {
      int row = row0 + wr * 64 + mi * 16 + lh * 4;
      int col = col0 + wc * 64 + ni * 16 + lr;
#pragma unroll
      for (int r = 0; r < 4; ++r) C[(size_t)(row + r) * N + col] = acc[mi][ni][r];
    }
  }
}

// ---------------- causal GQA flash attention v10: K AND V staged in LDS ------
// Paired schedule (R4): block does q-tiles {y, 31-y} = 33 units, 512 blocks,
// 2/CU co-resident, perfectly balanced, no merge. Per tile both K (64x256B)
// and V (128x128B) tiles are double-buffered in LDS via global_load_lds with
// G21 both-sides XOR swizzle -> PV reads are ~12cy ds_read_b128, no global
// latency on the critical path; the only vmcnt drain is the end-of-tile
// barrier, issued long after the async staging.
__global__ __launch_bounds__(256) void k_flash_attn(const u16* __restrict__ Q,
                                                    const u16* __restrict__ Kb,
                                                    const u16* __restrict__ Vt,
                                                    u16* __restrict__ O, int S, int H, int KH,
                                                    int Mtot) {
  const int bh = blockIdx.x;
  const int h = bh % H, b = bh / H;
  const int kvh = h / (H / KH);
  const int w = threadIdx.x >> 6, l = threadIdx.x & 63;
  const int lr = l & 15, lh = l >> 4;

  __shared__ alignas(16) char sK[2][16384];           // 64 kv x 256B, XOR-swizzled
  __shared__ alignas(16) char sV[2][16384];           // 128 d x 128B, XOR-swizzled
  __shared__ alignas(16) unsigned P_lds[4][16 * 32];  // per-wave packed P, XOR-swizzled
  unsigned* prow = P_lds[w] + lr * 32;
  const int xr = (lr & 7) << 2;

  v4f zz = {0.f, 0.f, 0.f, 0.f};
  const int strideK = KH * 128;
  const int strideKB = strideK * 2;
  const char* KheadB = (const char*)Kb + 2 * ((size_t)b * S * strideK + (size_t)kvh * 128);
  const char* VheadB = (const char*)Vt + 2 * ((size_t)(kvh * 128) * Mtot + (size_t)b * S);
  const size_t MtotB = (size_t)Mtot * 2;

  // stage K tile (64 rows x 256B) + V tile (128 rows x 128B) for kv0 into buf
  auto stage = [&](int kv0, int bufi) {
    const char* Kt = KheadB + (size_t)kv0 * strideKB;
#pragma unroll
    for (int j = 0; j < 4; ++j) {
      int jj = w * 4 + j;
      int ci = jj * 64 + l;
      int r = ci >> 4;                 // kv row 0..63
      int bc = (ci & 15) << 4;         // byte col 0..255
      const char* src = Kt + (size_t)r * strideKB + (bc ^ ((r & 15) << 4));
      __builtin_amdgcn_global_load_lds((const __attribute__((address_space(1))) void*)src,
                                       (__attribute__((address_space(3))) void*)(sK[bufi] + jj * 1024),
                                       16, 0, 0);
    }
    const char* Vt0 = VheadB + (size_t)kv0 * 2;
#pragma unroll
    for (int j = 0; j < 4; ++j) {
      int jj = w * 4 + j;
      int ci = jj * 64 + l;
      int r = ci >> 3;                 // d row 0..127
      int bc = (ci & 7) << 4;          // byte col 0..127
      const char* src = Vt0 + (size_t)r * MtotB + (bc ^ ((r & 7) << 4));
      __builtin_amdgcn_global_load_lds((const __attribute__((address_space(1))) void*)src,
                                       (__attribute__((address_space(3))) void*)(sV[bufi] + jj * 1024),
                                       16, 0, 0);
    }
  };

  for (int pp = 0; pp < 2; ++pp) {
    const int qt = (pp == 0) ? (int)blockIdx.y : (S / 64 - 1 - (int)blockIdx.y);
    const int q0 = qt * 64;
    const int nt = qt + 1;
    const int qi = q0 + w * 16 + lr;

    v8s qf[4];
    const u16* qp = Q + (size_t)(b * S + q0 + w * 16 + lr) * (size_t)(H * 128) + h * 128 + lh * 8;
#pragma unroll
    for (int c = 0; c < 4; ++c) qf[c] = *(const v8s*)(qp + c * 32);

    v4f o_acc[8];
#pragma unroll
    for (int df = 0; df < 8; ++df) o_acc[df] = zz;
    float m_run = -1e30f, l_run = 0.f;

    stage(0, 0);
    __syncthreads();

    int buf = 0;
    for (int t = 0; t < nt; ++t) {
      const int kv0 = t * 64;
      const bool lastTile = (t == nt - 1);
      const char* sKb = sK[buf];
      const char* sVb = sV[buf];

      // ---- QK^T swapped (C rows=kv, cols=q), K from LDS ----
      v4f sv[4];
      __builtin_amdgcn_s_setprio(1);
#pragma unroll
      for (int nf = 0; nf < 4; ++nf) {
        v4f a_ = zz;
        const int r = nf * 16 + lr;
#pragma unroll
        for (int c = 0; c < 4; ++c) {
          v8s kf = *(const v8s*)(sKb + r * 256 + ((lh * 16 + c * 64) ^ (lr << 4)));
          a_ = __builtin_amdgcn_mfma_f32_16x16x32_bf16(kf, qf[c], a_, 0, 0, 0);
        }
        sv[nf] = a_;
      }
      __builtin_amdgcn_s_setprio(0);

      // ---- stage next tile (async; drains only at end-of-tile barrier) ----
      if (t + 1 < nt) stage(kv0 + 64, buf ^ 1);

      // ---- in-lane online softmax (lane owns q=qi) ----
      if (lastTile) {
#pragma unroll
        for (int nf = 0; nf < 4; ++nf)
#pragma unroll
          for (int r = 0; r < 4; ++r)
            if (kv0 + nf * 16 + lh * 4 + r > qi) sv[nf][r] = -1e30f;
      }
      float pmax = -1e30f;
#pragma unroll
      for (int nf = 0; nf < 4; ++nf)
#pragma unroll
        for (int r = 0; r < 4; ++r) pmax = fmaxf(pmax, sv[nf][r]);
      pmax = fmaxf(pmax, __shfl_xor(pmax, 16, 64));
      pmax = fmaxf(pmax, __shfl_xor(pmax, 32, 64));
      if (!__all(pmax - m_run <= 8.0f)) {  // T13 defer-max
        float mnew = fmaxf(m_run, pmax);
        float corr = exp2f(m_run - mnew);
        l_run *= corr;
        m_run = mnew;
        float corrq[4];
#pragma unroll
        for (int r = 0; r < 4; ++r) corrq[r] = __shfl(corr, lh * 4 + r, 16);
#pragma unroll
        for (int df = 0; df < 8; ++df)
#pragma unroll
          for (int r = 0; r < 4; ++r) o_acc[df][r] *= corrq[r];
      }
      float rsum = 0.f;
#pragma unroll
      for (int nf = 0; nf < 4; ++nf)
#pragma unroll
        for (int r = 0; r < 4; ++r) {
          float pv = exp2f(sv[nf][r] - m_run);
          sv[nf][r] = pv;
          rsum += pv;
        }
      rsum += __shfl_xor(rsum, 16, 64);
      rsum += __shfl_xor(rsum, 32, 64);
      l_run += rsum;

      // ---- pack P -> per-wave LDS, reload as A-frags ----
#pragma unroll
      for (int nf = 0; nf < 4; ++nf) {
        v2u pw;
        pw[0] = pk2(sv[nf][0], sv[nf][1]);
        pw[1] = pk2(sv[nf][2], sv[nf][3]);
        *(v2u*)(prow + ((nf * 8 + lh * 2) ^ xr)) = pw;
      }
      asm volatile("s_waitcnt lgkmcnt(0)" ::: "memory");
      __builtin_amdgcn_sched_barrier(0);  // rule 18
      v8s ap[2];
#pragma unroll
      for (int c2 = 0; c2 < 2; ++c2) ap[c2] = *(const v8s*)(prow + ((c2 * 16 + lh * 4) ^ xr));

      // ---- PV: V fragments from LDS (swizzled ds_read_b128) ----
      __builtin_amdgcn_s_setprio(1);
#pragma unroll
      for (int df = 0; df < 8; ++df) {
        const int r = df * 16 + lr;
        const char* vrow = sVb + r * 128;
        const int key = (lr & 7) << 4;
#pragma unroll
        for (int c2 = 0; c2 < 2; ++c2) {
          v8s vf = *(const v8s*)(vrow + ((lh * 16 + c2 * 64) ^ key));
          o_acc[df] = __builtin_amdgcn_mfma_f32_16x16x32_bf16(ap[c2], vf, o_acc[df], 0, 0, 0);
        }
      }
      __builtin_amdgcn_s_setprio(0);

      __syncthreads();  // drains vmcnt -> next K+V staged; P_lds/buf reuse safe
      buf ^= 1;
    }

    // epilogue: normalize and store bf16
    float rl = 1.0f / l_run;
    float invq[4];
#pragma unroll
    for (int r = 0; r < 4; ++r) invq[r] = __shfl(rl, lh * 4 + r, 16);
    u16* op = O + (size_t)(b * S + q0 + w * 16 + lh * 4) * (size_t)(H * 128) + h * 128;
#pragma unroll
    for (int r = 0; r < 4; ++r)
#pragma unroll
      for (int df = 0; df < 8; ++df)
        op[(size_t)r * (H * 128) + df * 16 + lr] = f2bf(o_acc[df][r] * invq[r]);
  }
}

extern "C" void kernel_launch(void* const* d_in, const int* in_sizes, int n_in, void* d_out,
                              int out_size, void* d_ws, size_t ws_size, hipStream_t stream) {
  const float* x = (const float*)d_in[0];
  const float* Wq = (const float*)d_in[1];
  const float* Wk = (const float*)d_in[2];
  const float* Wv = (const float*)d_in[3];
  const float* Wp = (const float*)d_in[4];
  const float* gain = (const float*)d_in[5];
  float* out = (float*)d_out;

  const int B = 2, S = 2048, D = 2048, H = 16, KH = 4;
  const int M = B * S;
  const int KVD = KH * 128;
  const int NQKV = D + 2 * KVD;  // 3072

  char* w = (char*)d_ws;
  u16* x_bf = (u16*)w;   w += (size_t)M * D * 2;
  u16* wqkv = (u16*)w;   w += (size_t)NQKV * D * 2;
  u16* wp_bf = (u16*)w;  w += (size_t)D * D * 2;
  u16* q_bf = (u16*)w;   w += (size_t)M * D * 2;
  u16* k_bf = (u16*)w;   w += (size_t)M * KVD * 2;
  u16* v_t = (u16*)w;    w += (size_t)M * KVD * 2;
  u16* ao_bf = (u16*)w;  w += (size_t)M * D * 2;
  float* cosT = (float*)w; w += (size_t)S * 64 * 4;
  float* sinT = (float*)w; w += (size_t)S * 64 * 4;
  if ((size_t)(w - (char*)d_ws) > ws_size) return;

  k_cast_bf16<<<(M * D / 4 + 255) / 256, 256, 0, stream>>>(x, x_bf, M * D / 4);
  {
    int na4 = D * D / 4, nb4 = KVD * D / 4, nc4 = KVD * D / 4, nd4 = D * D / 4;
    int tot = na4 + nb4 + nc4 + nd4;
    k_cast_w<<<(tot + 255) / 256, 256, 0, stream>>>(
        Wq, Wk, Wv, Wp, wqkv, wqkv + (size_t)D * D, wqkv + (size_t)(D + KVD) * D, wp_bf,
        na4, nb4, nc4, nd4);
  }

  double scale = (double)S / 1024.0;
  double base = (S > 1024) ? 10000.0 * pow(scale, 128.0 / 126.0) : 10000.0;
  float l2b = (float)(log(base) / log(2.0));
  k_rope_tab<<<S * 64 / 256, 256, 0, stream>>>(cosT, sinT, l2b);

  dim3 blk(256);
  dim3 gqkv(NQKV / 128, M / 128);  // 24 x 32 = 768 blocks
  k_gemm_qkv<<<gqkv, blk, 0, stream>>>(x_bf, wqkv, q_bf, k_bf, v_t, M, D);

  float qscale = 1.4426950408889634f / sqrtf(128.0f);
  k_rmsnorm_rope<<<(M * H) / 4, 256, 0, stream>>>(q_bf, cosT, sinT, gain, H, S, qscale);
  k_rmsnorm_rope<<<(M * KH) / 4, 256, 0, stream>>>(k_bf, cosT, sinT, nullptr, KH, S, 1.0f);

  dim3 ga(B * H, S / 128);  // 512 blocks, paired q-tiles {y, 31-y} = 33 units each
  k_flash_attn<<<ga, blk, 0, stream>>>(q_bf, k_bf, v_t, ao_bf, S, H, KH, M);

  dim3 gp(D / 128, M / 128);
  k_gemm_bt<<<gp, blk, 0, stream>>>(ao_bf, wp_bf, out, M, D, D);
}